// Round 10
// baseline (269.009 us; speedup 1.0000x reference)
//
#include <hip/hip_runtime.h>
#include <cstdint>
#include <cstddef>

typedef unsigned short u16;
typedef __attribute__((ext_vector_type(8))) short bf16x8;
typedef __attribute__((ext_vector_type(4))) float f32x4;

// ---------- bf16 helpers ----------
__device__ __forceinline__ float b2f(u16 u) {
  union { uint32_t i; float f; } x; x.i = ((uint32_t)u) << 16; return x.f;
}
__device__ __forceinline__ u16 f2b(float f) {
  union { float f; uint32_t i; } x; x.f = f;
  uint32_t u = x.i;
  u += 0x7fffu + ((u >> 16) & 1u);   // RNE
  return (u16)(u >> 16);
}
__device__ __forceinline__ void load8(const void* p, size_t idx, bool f32, float o[8]) {
  if (f32) {
    const float4* fp = (const float4*)((const float*)p + idx);
    float4 x = fp[0], y = fp[1];
    o[0] = x.x; o[1] = x.y; o[2] = x.z; o[3] = x.w;
    o[4] = y.x; o[5] = y.y; o[6] = y.z; o[7] = y.w;
  } else {
    uint4 w = *(const uint4*)((const u16*)p + idx);
    uint32_t ww[4] = {w.x, w.y, w.z, w.w};
#pragma unroll
    for (int q = 0; q < 4; q++) {
      o[2 * q]     = b2f((u16)(ww[q] & 0xffffu));
      o[2 * q + 1] = b2f((u16)(ww[q] >> 16));
    }
  }
}
__device__ __forceinline__ void store8_bf16(u16* p, size_t idx, const float o[8]) {
  uint32_t w[4];
#pragma unroll
  for (int q = 0; q < 4; q++)
    w[q] = (uint32_t)f2b(o[2 * q]) | ((uint32_t)f2b(o[2 * q + 1]) << 16);
  *(uint4*)(p + idx) = make_uint4(w[0], w[1], w[2], w[3]);
}

// per-block dtype detect (bf16 vs f32) from raw bits of l; broadcast via LDS.
__device__ __forceinline__ bool detect_f32(const u16* lb, int* ldsflag, int tid) {
  if (tid < 64) {
    int bad = 0;
    for (int i = tid; i < 1024; i += 64) {
      float f = b2f(lb[i]);
      if (!(fabsf(f) <= 1.0e4f)) bad = 1;   // catches NaN too
    }
    int any = __any(bad);
    if (tid == 0) *ldsflag = any;
  }
  __syncthreads();
  const bool r = (*ldsflag != 0);
  __syncthreads();
  return r;
}

// ================= fragment-major X with sigma bank-swizzle =================
// chunk = (row>>4)*16 + (k>>5); granule G = cq*16 + (row&15) where cq=(k>>3)&3;
// sigma: G' = G ^ (chunk&7) spreads the per-row all-column access uniformly
// across the 8 granule-columns of the 32 LDS banks (chunk&7 == kc&7 since the
// row part of chunk is a multiple of 16). MFMA frag reads (lane -> granule
// lane^(kb&7)) remain a permutation -> conflict-free.
__device__ __forceinline__ int xsw(int chunk, int G) {
  return (chunk << 9) + (((G) ^ (chunk & 7)) << 3);
}

// ---------- weight transpose -> frag-major WtF (verbatim, global = no sigma) --
__global__ __launch_bounds__(1024)
void transw_k(const void* __restrict__ fc1W, const void* __restrict__ convW,
              const u16* __restrict__ lbits, u16* __restrict__ WtF)
{
  __shared__ u16 tile[32][33];
  __shared__ int flagS;
  const int tx = threadIdx.x, ty = threadIdx.y;
  const int tid = ty * 32 + tx;
  const bool f32 = detect_f32(lbits, &flagS, tid);
  const int w = blockIdx.z;
  const void* W = (w == 0) ? fc1W : convW;
  const size_t base = (w == 0) ? 0 : (size_t)(w - 1) * 262144;
  const int bx = blockIdx.x, by = blockIdx.y;
  const size_t i = base + (size_t)(by * 32 + ty) * 512 + (bx * 32 + tx);
  float val = f32 ? ((const float*)W)[i] : b2f(((const u16*)W)[i]);
  tile[ty][tx] = f2b(val);   // tile[ty][tx] = W[by*32+ty][bx*32+tx]
  __syncthreads();
  const int e = tid & 7, l16 = (tid >> 3) & 15, q = (tid >> 7) & 3, nbp = tid >> 9;
  const u16 vv = tile[q * 8 + e][nbp * 16 + l16];
  WtF[(size_t)w * 262144 + ((size_t)((bx * 2 + nbp) * 16 + by)) * 512 +
      (q * 16 + l16) * 8 + e] = vv;
}

// ---------- persistent per-dialogue fused kernel ----------
__device__ __forceinline__ void gemm_layer(f32x4 (&acc)[8][4], const u16* Xs,
                                           const u16* __restrict__ WL,
                                           int nt, int lane)
{
  const int lane8 = lane * 8;
  bf16x8 w0[4], w1[4];
#pragma unroll
  for (int nb = 0; nb < 4; ++nb) {
    w0[nb] = *(const bf16x8*)(WL + (((nt * 4 + nb) * 16 + 0) << 9) + lane8);
    w1[nb] = *(const bf16x8*)(WL + (((nt * 4 + nb) * 16 + 1) << 9) + lane8);
  }
#pragma unroll
  for (int kb = 0; kb < 16; ++kb) {
    bf16x8 w2[4];
    if (kb < 14) {                       // 2-deep prefetch covers L2 latency
#pragma unroll
      for (int nb = 0; nb < 4; ++nb)
        w2[nb] = *(const bf16x8*)(WL + (((nt * 4 + nb) * 16 + kb + 2) << 9) + lane8);
    }
    bf16x8 af[4];
#pragma unroll
    for (int rb = 0; rb < 4; ++rb)
      af[rb] = *(const bf16x8*)&Xs[xsw(rb * 16 + kb, lane)];
    __builtin_amdgcn_s_setprio(1);
#pragma unroll
    for (int rb = 0; rb < 4; ++rb)
#pragma unroll
      for (int nb = 0; nb < 4; ++nb)
        acc[rb][nb] = __builtin_amdgcn_mfma_f32_16x16x32_bf16(af[rb], w0[nb],
                                                              acc[rb][nb], 0, 0, 0);
    __builtin_amdgcn_s_setprio(0);
#pragma unroll
    for (int rb = 0; rb < 4; ++rb)
      af[rb] = *(const bf16x8*)&Xs[xsw((rb + 4) * 16 + kb, lane)];
    __builtin_amdgcn_s_setprio(1);
#pragma unroll
    for (int rb = 0; rb < 4; ++rb)
#pragma unroll
      for (int nb = 0; nb < 4; ++nb)
        acc[rb + 4][nb] = __builtin_amdgcn_mfma_f32_16x16x32_bf16(af[rb], w0[nb],
                                                                  acc[rb + 4][nb], 0, 0, 0);
    __builtin_amdgcn_s_setprio(0);
#pragma unroll
    for (int nb = 0; nb < 4; ++nb) { w0[nb] = w1[nb]; w1[nb] = w2[nb]; }
  }
}

__device__ __forceinline__ void bias_add(f32x4 (&acc)[8][4], const void* bptr,
                                         int boff, bool f32io, int nt, int l16)
{
#pragma unroll
  for (int nb = 0; nb < 4; ++nb) {
    const int col = nt * 64 + nb * 16 + l16;
    const float b = f32io ? ((const float*)bptr)[boff + col]
                          : b2f(((const u16*)bptr)[boff + col]);
#pragma unroll
    for (int rb = 0; rb < 8; ++rb)
#pragma unroll
      for (int r = 0; r < 4; ++r) acc[rb][nb][r] += b;
  }
}

// gb-write (f2b(acc) -> X, wave's own 64 cols) + column sums FROM REGISTERS:
// per-lane partial sums of the rounded values (predicated by modality), then
// butterfly shfl_xor across the 4 quads (quads hold disjoint rows of the same
// column). Replaces the 16-way-conflicted 120-read LDS colsum entirely.
__device__ __forceinline__ void gb_write_colsum(const f32x4 (&acc)[8][4], u16* Xs,
                                                float* Bs, int nt, int quad, int l16)
{
  float ps0[4], ps1[4], ps2[4];
#pragma unroll
  for (int nb = 0; nb < 4; ++nb) { ps0[nb] = 0.f; ps1[nb] = 0.f; ps2[nb] = 0.f; }
#pragma unroll
  for (int nb = 0; nb < 4; ++nb) {
    const int c = nt * 64 + nb * 16 + l16;
    const int kc = c >> 5, cq = (c >> 3) & 3, e = c & 7;
#pragma unroll
    for (int rb = 0; rb < 8; ++rb)
#pragma unroll
      for (int r = 0; r < 4; ++r) {
        const int row = rb * 16 + quad * 4 + r;
        if (row < 120) {
          const u16 hb = f2b(acc[rb][nb][r]);
          Xs[xsw(rb * 16 + kc, cq * 16 + quad * 4 + r) + e] = hb;
          const float fv = b2f(hb);
          if (row < 40)      ps0[nb] += fv;
          else if (row < 80) ps1[nb] += fv;
          else               ps2[nb] += fv;
        }
      }
  }
#pragma unroll
  for (int nb = 0; nb < 4; ++nb) {
    ps0[nb] += __shfl_xor(ps0[nb], 16); ps0[nb] += __shfl_xor(ps0[nb], 32);
    ps1[nb] += __shfl_xor(ps1[nb], 16); ps1[nb] += __shfl_xor(ps1[nb], 32);
    ps2[nb] += __shfl_xor(ps2[nb], 16); ps2[nb] += __shfl_xor(ps2[nb], 32);
  }
  if (quad < 3) {
#pragma unroll
    for (int nb = 0; nb < 4; ++nb) {
      const float s = (quad == 0) ? ps0[nb] : ((quad == 1) ? ps1[nb] : ps2[nb]);
      Bs[quad * 512 + nt * 64 + nb * 16 + l16] = s;
    }
  }
}

// agg in place, vectorized: lane owns 8 consecutive cols (kc=lane>>2, cq=lane&3);
// waves partition t (5 each). Per t: 3 uint4 reads + 3 uint4 writes, uniform
// granule-column distribution under the sigma swizzle.
__device__ __forceinline__ void agg_update(u16* Xs, const float* Bs, int nt, int lane)
{
  const int kc = lane >> 2, cq = lane & 3;
  const int c0 = kc * 32 + cq * 8;
  float b0[8], b1[8], b2[8];
  *(float4*)&b0[0] = *(const float4*)&Bs[c0];
  *(float4*)&b0[4] = *(const float4*)&Bs[c0 + 4];
  *(float4*)&b1[0] = *(const float4*)&Bs[512 + c0];
  *(float4*)&b1[4] = *(const float4*)&Bs[512 + c0 + 4];
  *(float4*)&b2[0] = *(const float4*)&Bs[1024 + c0];
  *(float4*)&b2[4] = *(const float4*)&Bs[1024 + c0 + 4];
  const float inv42 = 1.0f / 42.0f;
#pragma unroll
  for (int i = 0; i < 5; ++i) {
    const int t = nt * 5 + i;
    const int r1 = 40 + t, r2 = 80 + t;
    const int i0 = xsw((t  >> 4) * 16 + kc, cq * 16 + (t  & 15));
    const int i1 = xsw((r1 >> 4) * 16 + kc, cq * 16 + (r1 & 15));
    const int i2 = xsw((r2 >> 4) * 16 + kc, cq * 16 + (r2 & 15));
    uint4 u0 = *(const uint4*)&Xs[i0];
    uint4 u1 = *(const uint4*)&Xs[i1];
    uint4 u2 = *(const uint4*)&Xs[i2];
    uint32_t a0[4] = {u0.x, u0.y, u0.z, u0.w};
    uint32_t a1[4] = {u1.x, u1.y, u1.z, u1.w};
    uint32_t a2[4] = {u2.x, u2.y, u2.z, u2.w};
    float f0[8], f1[8], f2[8];
#pragma unroll
    for (int q = 0; q < 4; ++q) {
      f0[2*q] = b2f((u16)(a0[q] & 0xffffu)); f0[2*q+1] = b2f((u16)(a0[q] >> 16));
      f1[2*q] = b2f((u16)(a1[q] & 0xffffu)); f1[2*q+1] = b2f((u16)(a1[q] >> 16));
      f2[2*q] = b2f((u16)(a2[q] & 0xffffu)); f2[2*q+1] = b2f((u16)(a2[q] >> 16));
    }
    uint32_t p0[4], p1[4], p2[4];
#pragma unroll
    for (int q = 0; q < 4; ++q) {
      const float o0a = (b0[2*q]   + f1[2*q]   + f2[2*q])   * inv42;
      const float o0b = (b0[2*q+1] + f1[2*q+1] + f2[2*q+1]) * inv42;
      const float o1a = (b1[2*q]   + f0[2*q]   + f2[2*q])   * inv42;
      const float o1b = (b1[2*q+1] + f0[2*q+1] + f2[2*q+1]) * inv42;
      const float o2a = (b2[2*q]   + f0[2*q]   + f1[2*q])   * inv42;
      const float o2b = (b2[2*q+1] + f0[2*q+1] + f1[2*q+1]) * inv42;
      p0[q] = (uint32_t)f2b(o0a) | ((uint32_t)f2b(o0b) << 16);
      p1[q] = (uint32_t)f2b(o1a) | ((uint32_t)f2b(o1b) << 16);
      p2[q] = (uint32_t)f2b(o2a) | ((uint32_t)f2b(o2b) << 16);
    }
    *(uint4*)&Xs[i0] = make_uint4(p0[0], p0[1], p0[2], p0[3]);
    *(uint4*)&Xs[i1] = make_uint4(p1[0], p1[1], p1[2], p1[3]);
    *(uint4*)&Xs[i2] = make_uint4(p2[0], p2[1], p2[2], p2[3]);
  }
}

// ---- coalesced writeout: acc -> LDS f32 scratch (3 passes of 40 rows) ->
// wide global stores. S aliases Xs (X dead at call sites; scratch bytes
// [0, 82560) never touch the pad-row chunks at [114688, 131072)).
__device__ __forceinline__ void writeout_co(void* outv, const f32x4 (&acc)[8][4],
                                            float* S, int d, int cbase, bool f32io,
                                            int nt, int quad, int l16, int tid)
{
  const int rg = tid >> 6;          // 0..7
  const int cs = (tid & 63) * 8;    // col base for the read phase
#pragma unroll
  for (int p = 0; p < 3; ++p) {
    const int p0 = p * 40;
    __syncthreads();                // prior reads of Xs/S complete
#pragma unroll
    for (int rb = 0; rb < 8; ++rb)
#pragma unroll
      for (int r = 0; r < 4; ++r) {
        const int row = rb * 16 + quad * 4 + r;
        const int lr = row - p0;
        if (lr >= 0 && lr < 40) {
#pragma unroll
          for (int nb = 0; nb < 4; ++nb)
            S[lr * 516 + nt * 64 + nb * 16 + l16] = acc[rb][nb][r];
        }
      }
    __syncthreads();
#pragma unroll
    for (int it = 0; it < 5; ++it) {
      const int lr = it * 8 + rg;   // t = lr, mod = p
      const size_t ob = (size_t)(d * 40 + lr) * 4608 + (size_t)p * 1536 + cbase + cs;
      const float* sp = &S[lr * 516 + cs];
      if (f32io) {
        float4 v0 = *(const float4*)sp, v1 = *(const float4*)(sp + 4);
        float* op = (float*)outv + ob;
        *(float4*)op = v0; *(float4*)(op + 4) = v1;
      } else {
        float vals[8];
#pragma unroll
        for (int q2 = 0; q2 < 8; ++q2) vals[q2] = sp[q2];
        store8_bf16((u16*)outv, ob, vals);
      }
    }
  }
}

__global__ __launch_bounds__(512, 2)
void fused_k(const void* __restrict__ a, const void* __restrict__ v,
             const void* __restrict__ l, const void* __restrict__ qmask,
             const void* __restrict__ spk, const void* __restrict__ fc1b,
             const void* __restrict__ convb, const u16* __restrict__ WtF,
             void* __restrict__ outv)
{
  __shared__ __align__(16) u16 Xs[65536];   // 131072 B, sigma-swizzled frag X
  __shared__ __align__(16) float Bs[1536];  // 6144 B col-sums per modality
  __shared__ int flagS;
  const int tid = threadIdx.x;
  const bool f32io = detect_f32((const u16*)l, &flagS, tid);
  const int d = blockIdx.x;
  const int lane = tid & 63, nt = tid >> 6;
  const int quad = lane >> 4, l16 = lane & 15;

  // ---- feats phase: inputs -> d_out cols [0,512) + X (bf16 frag, sigma) ----
  {
    const int cs = (tid & 63) * 8;
    const int rg = tid >> 6;
    const int kcf = cs >> 5, cqf = (cs >> 3) & 3;
#pragma unroll
    for (int it = 0; it < 15; ++it) {
      const int r = it * 8 + rg;            // 0..119
      const int mod = r / 40, t = r - mod * 40;
      const int u = d * 40 + t;
      float vals[8];
      const void* srcp = (mod == 1) ? a : ((mod == 2) ? v : l);
      load8(srcp, (size_t)u * 512 + cs, f32io, vals);
      if (mod == 0) {
        const int qi = (t * 128 + d) * 2;
        float q0 = f32io ? ((const float*)qmask)[qi]     : b2f(((const u16*)qmask)[qi]);
        float q1 = f32io ? ((const float*)qmask)[qi + 1] : b2f(((const u16*)qmask)[qi + 1]);
        const int sidx = (q1 > q0) ? 1 : 0;   // np.argmax tie -> first index
        float sv[8];
        load8(spk, (size_t)sidx * 512 + cs, f32io, sv);
#pragma unroll
        for (int j = 0; j < 8; ++j) vals[j] += sv[j];
      }
      const size_t oidx = (size_t)u * 4608 + (size_t)mod * 1536 + cs;
      if (f32io) {
        float4* op = (float4*)((float*)outv + oidx);
        op[0] = make_float4(vals[0], vals[1], vals[2], vals[3]);
        op[1] = make_float4(vals[4], vals[5], vals[6], vals[7]);
      } else {
        store8_bf16((u16*)outv, oidx, vals);
      }
      uint32_t w[4];
#pragma unroll
      for (int p = 0; p < 4; ++p)
        w[p] = (uint32_t)f2b(vals[2 * p]) | ((uint32_t)f2b(vals[2 * p + 1]) << 16);
      *(uint4*)&Xs[xsw((r >> 4) * 16 + kcf, cqf * 16 + (r & 15))] =
          make_uint4(w[0], w[1], w[2], w[3]);
    }
    const int rz = 120 + rg;                 // zero pad rows 120..127
    *(uint4*)&Xs[xsw((rz >> 4) * 16 + kcf, cqf * 16 + (rz & 15))] =
        make_uint4(0, 0, 0, 0);
  }
  __syncthreads();

  // ---- layer 0: x1 = feats @ fc1W + fc1b ----
  f32x4 acc[8][4];
#pragma unroll
  for (int rb = 0; rb < 8; ++rb)
#pragma unroll
    for (int nb = 0; nb < 4; ++nb) {
      f32x4 z = {0.f, 0.f, 0.f, 0.f};
      acc[rb][nb] = z;
    }
  gemm_layer(acc, Xs, WtF, nt, lane);
  bias_add(acc, fc1b, 0, f32io, nt, l16);
  // x1 -> d_out cols [512,1024); X(feats) dead -> Xs doubles as f32 scratch
  writeout_co(outv, acc, (float*)Xs, d, 512, f32io, nt, quad, l16, tid);

  // ---- 4 GCN layers: acc += agg(f2b(acc)) @ Wk + bk ----
#pragma unroll 1
  for (int L = 0; L < 4; ++L) {
    __syncthreads();                 // scratch/X reads complete before overwrite
    gb_write_colsum(acc, Xs, Bs, nt, quad, l16);
    __syncthreads();                 // X(gb) + Bs visible to all waves
    agg_update(Xs, Bs, nt, lane);    // t-partitioned, vectorized, in place
    __syncthreads();                 // X(agg) complete
    gemm_layer(acc, Xs, WtF + (size_t)(L + 1) * 262144, nt, lane);  // C-init = g
    bias_add(acc, convb, L * 512, f32io, nt, l16);
  }
  // gnn_out -> d_out cols [1024,1536); X dead again
  writeout_co(outv, acc, (float*)Xs, d, 1024, f32io, nt, quad, l16, tid);
}

// ---------- launch ----------
extern "C" void kernel_launch(void* const* d_in, const int* in_sizes, int n_in,
                              void* d_out, int out_size, void* d_ws, size_t ws_size,
                              hipStream_t stream)
{
  const void* a     = d_in[0];
  const void* v     = d_in[1];
  const void* l     = d_in[2];
  const void* qmask = d_in[3];
  const void* spk   = d_in[4];
  const void* fc1W  = d_in[5];
  const void* fc1b  = d_in[6];
  const void* convW = d_in[7];
  const void* convb = d_in[8];

  u16* WtF = (u16*)d_ws;                     // 5*512*512*2 = 2,621,440 B

  // 1) weights -> frag-major WtF (dtype detect folded in)
  transw_k<<<dim3(16, 16, 5), dim3(32, 32), 0, stream>>>(fc1W, convW,
                                                         (const u16*)l, WtF);

  // 2) entire per-dialogue pipeline, one persistent kernel (128 blocks)
  fused_k<<<128, 512, 0, stream>>>(a, v, l, qmask, spk, fc1b, convb, WtF, d_out);
}